// Round 5
// baseline (1704.633 us; speedup 1.0000x reference)
//
#include <hip/hip_runtime.h>

// LightGCN 3-layer propagation: atomic-free bucket counting-sort + LDS-tile SpMM.
// out layout: [4, N_NODES, DIM] f32.
//   layer 0 = embeddings (copy)
//   layer l = SpMM(layer l-1):  y[d] = sum_{e: dst(e)=d} w[e] * x[src(e)]
//
// R4 post-mortem: per-edge global atomics on 782 bucket counters serialized
// (~24k RMWs per 64B line) -> 327 us histogram. R5 rebuild:
//  (1) counting sort by 128-node bucket with ZERO global atomics:
//      per-chunk LDS histograms -> exclusive scan of [bucket][chunk] counts
//      (in-place) -> LDS-cursor scatter into exact slots.
//  (2) spmm: one block per bucket, accumulate into a 32KB LDS tile via
//      ds_add_f32 (lane=dim -> conflict-free), one coalesced 32KB store.
//      No per-dst CSR, no deg/off/cur at all.

#define N_NODES 100000
#define DIM 64
#define BSHIFT 7
#define BSIZE 128
#define NB ((N_NODES + BSIZE - 1) / BSIZE)   // 782 buckets
#define NCHUNKS 256
#define SCAN_CHUNK 1024

// ---------------- pass 1: per-chunk bucket histogram (LDS, no global atomics)

__global__ void chunk_hist_kernel(const int* __restrict__ edst,
                                  int* __restrict__ counts, int E) {
    __shared__ int hist[NB];
    for (int i = threadIdx.x; i < NB; i += blockDim.x) hist[i] = 0;
    __syncthreads();
    int chunk = blockIdx.x;
    int per = (E + NCHUNKS - 1) / NCHUNKS;
    int s = chunk * per;
    int e = min(E, s + per);
    for (int i = s + threadIdx.x; i < e; i += blockDim.x)
        atomicAdd(&hist[edst[i] >> BSHIFT], 1);          // LDS atomic, ~6/bucket
    __syncthreads();
    for (int i = threadIdx.x; i < NB; i += blockDim.x)
        counts[i * NCHUNKS + chunk] = hist[i];           // bucket-major layout
}

// ---------------- exclusive scan over counts[NB*NCHUNKS], in place -----------

__global__ void scan1_kernel(int* __restrict__ data, int* __restrict__ bsum, int n) {
    __shared__ int sdata[256];
    int tid = threadIdx.x;
    int base = blockIdx.x * SCAN_CHUNK + tid * 4;
    int v[4];
    #pragma unroll
    for (int i = 0; i < 4; ++i) v[i] = (base + i < n) ? data[base + i] : 0;
    int tsum = v[0] + v[1] + v[2] + v[3];
    sdata[tid] = tsum;
    __syncthreads();
    for (int d = 1; d < 256; d <<= 1) {
        int t = (tid >= d) ? sdata[tid - d] : 0;
        __syncthreads();
        sdata[tid] += t;
        __syncthreads();
    }
    int excl = sdata[tid] - tsum;
    if (tid == 255) bsum[blockIdx.x] = sdata[255];
    int run = excl;
    #pragma unroll
    for (int i = 0; i < 4; ++i) {
        if (base + i < n) data[base + i] = run;          // in-place exclusive
        run += v[i];
    }
}

__global__ void scan2_kernel(int* __restrict__ bsum, int nb) {
    __shared__ int s[256];
    int tid = threadIdx.x;
    int v = (tid < nb) ? bsum[tid] : 0;
    s[tid] = v;
    __syncthreads();
    for (int d = 1; d < 256; d <<= 1) {
        int t = (tid >= d) ? s[tid - d] : 0;
        __syncthreads();
        s[tid] += t;
        __syncthreads();
    }
    if (tid < nb) bsum[tid] = s[tid] - v;
}

__global__ void scan3_kernel(int* __restrict__ data, const int* __restrict__ bsum, int n) {
    int i = blockIdx.x * blockDim.x + threadIdx.x;
    if (i < n) data[i] += bsum[i / SCAN_CHUNK];
}

// ---------------- pass 2: scatter into exact slots (LDS cursors) -------------
// pair: { (src << 7) | (dst & 127), weight_bits }   (src < 2^17 fits in 25 bits)

__global__ void chunk_scatter_kernel(const int* __restrict__ esrc,
                                     const int* __restrict__ edst,
                                     const float* __restrict__ ew,
                                     const int* __restrict__ base,
                                     int2* __restrict__ pairs, int E) {
    __shared__ int cursor[NB];
    int chunk = blockIdx.x;
    for (int i = threadIdx.x; i < NB; i += blockDim.x)
        cursor[i] = base[i * NCHUNKS + chunk];
    __syncthreads();
    int per = (E + NCHUNKS - 1) / NCHUNKS;
    int s = chunk * per;
    int e = min(E, s + per);
    for (int i = s + threadIdx.x; i < e; i += blockDim.x) {
        int d = edst[i];
        int b = d >> BSHIFT;
        int slot = atomicAdd(&cursor[b], 1);             // LDS atomic
        int2 pr;
        pr.x = (esrc[i] << BSHIFT) | (d & (BSIZE - 1));
        pr.y = __float_as_int(ew[i]);
        pairs[slot] = pr;
    }
}

// ---------------- SpMM: one block per bucket, LDS-tile accumulation ----------

__global__ void __launch_bounds__(256) spmm_bucket_kernel(
        const float* __restrict__ x, const int2* __restrict__ pairs,
        const int* __restrict__ base, float* __restrict__ y, int E) {
    __shared__ float tile[BSIZE * DIM];                  // 32 KB
    int b = blockIdx.x;
    int off = base[b * NCHUNKS];
    int end = (b + 1 < NB) ? base[(b + 1) * NCHUNKS] : E;

    float4* tile4 = (float4*)tile;
    for (int i = threadIdx.x; i < BSIZE * DIM / 4; i += blockDim.x)
        tile4[i] = make_float4(0.f, 0.f, 0.f, 0.f);
    __syncthreads();

    int lane = threadIdx.x & 63;
    int wv = threadIdx.x >> 6;                           // 4 waves per block
    int len = end - off;
    int per = (len + 3) >> 2;                            // contiguous sub-range per wave
    int s = off + wv * per;
    int e = min(end, s + per);

    int k = s;
    for (; k + 3 < e; k += 4) {                          // 4 independent gather chains
        int2 p0 = pairs[k];
        int2 p1 = pairs[k + 1];
        int2 p2 = pairs[k + 2];
        int2 p3 = pairs[k + 3];
        float v0 = x[(size_t)(p0.x >> BSHIFT) * DIM + lane];
        float v1 = x[(size_t)(p1.x >> BSHIFT) * DIM + lane];
        float v2 = x[(size_t)(p2.x >> BSHIFT) * DIM + lane];
        float v3 = x[(size_t)(p3.x >> BSHIFT) * DIM + lane];
        atomicAdd(&tile[(p0.x & (BSIZE - 1)) * DIM + lane], __int_as_float(p0.y) * v0);
        atomicAdd(&tile[(p1.x & (BSIZE - 1)) * DIM + lane], __int_as_float(p1.y) * v1);
        atomicAdd(&tile[(p2.x & (BSIZE - 1)) * DIM + lane], __int_as_float(p2.y) * v2);
        atomicAdd(&tile[(p3.x & (BSIZE - 1)) * DIM + lane], __int_as_float(p3.y) * v3);
    }
    for (; k < e; ++k) {
        int2 p = pairs[k];
        float v = x[(size_t)(p.x >> BSHIFT) * DIM + lane];
        atomicAdd(&tile[(p.x & (BSIZE - 1)) * DIM + lane], __int_as_float(p.y) * v);
    }
    __syncthreads();

    // Coalesced 32 KB store (last bucket: only 32 valid nodes).
    for (int i = threadIdx.x; i < BSIZE * DIM / 4; i += blockDim.x) {
        int node = b * BSIZE + (i >> 4);
        if (node < N_NODES)
            ((float4*)y)[(size_t)node * (DIM / 4) + (i & 15)] = tile4[i];
    }
}

// ---------------- fallback (atomic path, if ws too small) --------------------

__global__ void spmm_atomic_kernel(const float* __restrict__ x, const float* __restrict__ ew,
                                   const int* __restrict__ esrc, const int* __restrict__ edst,
                                   float* __restrict__ y, int n_edges) {
    long long tid = (long long)blockIdx.x * blockDim.x + threadIdx.x;
    int e = (int)(tid >> 6);
    int d = (int)(tid & 63);
    if (e >= n_edges) return;
    int s = esrc[e]; int t = edst[e]; float w = ew[e];
    atomicAdd(&y[(long long)t * DIM + d], w * x[(long long)s * DIM + d]);
}

extern "C" void kernel_launch(void* const* d_in, const int* in_sizes, int n_in,
                              void* d_out, int out_size, void* d_ws, size_t ws_size,
                              hipStream_t stream) {
    const float* emb  = (const float*)d_in[0];
    const float* ew   = (const float*)d_in[1];
    const int*   esrc = (const int*)d_in[2];
    const int*   edst = (const int*)d_in[3];
    float* out = (float*)d_out;

    const int E = in_sizes[1];
    const size_t layer_elems = (size_t)N_NODES * DIM;

    // ws layout: pairs (E int2) | counts/base (NB*NCHUNKS int, scanned in place) | bsum
    const int scan_n = NB * NCHUNKS;                       // 200192
    const int nscan = (scan_n + SCAN_CHUNK - 1) / SCAN_CHUNK;  // 196
    size_t need = (size_t)E * 8 + (size_t)scan_n * 4 + (size_t)nscan * 4 + 256;

    // Layer 0: copy embeddings.
    hipMemcpyAsync(out, emb, layer_elems * sizeof(float), hipMemcpyDeviceToDevice, stream);

    if (ws_size >= need) {
        char* w = (char*)d_ws;
        int2* pairs = (int2*)w;
        int* counts = (int*)(w + (size_t)E * 8);           // becomes `base` after scan
        int* bsum   = counts + scan_n;

        chunk_hist_kernel<<<NCHUNKS, 256, 0, stream>>>(edst, counts, E);
        scan1_kernel<<<nscan, 256, 0, stream>>>(counts, bsum, scan_n);
        scan2_kernel<<<1, 256, 0, stream>>>(bsum, nscan);
        scan3_kernel<<<(scan_n + 255) / 256, 256, 0, stream>>>(counts, bsum, scan_n);
        chunk_scatter_kernel<<<NCHUNKS, 256, 0, stream>>>(esrc, edst, ew, counts, pairs, E);

        for (int l = 1; l <= 3; ++l) {
            spmm_bucket_kernel<<<NB, 256, 0, stream>>>(
                out + (size_t)(l - 1) * layer_elems, pairs, counts,
                out + (size_t)l * layer_elems, E);
        }
    } else {
        hipMemsetAsync(out + layer_elems, 0, 3 * layer_elems * sizeof(float), stream);
        const long long total_threads = (long long)E * 64;
        const int blocks = (int)((total_threads + 255) / 256);
        for (int l = 1; l <= 3; ++l) {
            spmm_atomic_kernel<<<blocks, 256, 0, stream>>>(
                out + (size_t)(l - 1) * layer_elems, ew, esrc, edst,
                out + (size_t)l * layer_elems, E);
        }
    }
}